// Round 8
// baseline (532.701 us; speedup 1.0000x reference)
//
#include <hip/hip_runtime.h>
#include <hip/hip_bf16.h>

#define N_NODES 20000
#define E_EDGES 640000
#define DIM 128
#define CAP 192
#define EPB 64    // edges per block in edge_kernel
#define NPB 8     // nodes per block in node_kernel
#define XST 264   // padded ushort stride for [64][256] LDS tile

typedef __attribute__((ext_vector_type(8))) short bf16x8;
typedef __attribute__((ext_vector_type(4))) float f32x4;

#define LOG2E 1.44269504f
__device__ __forceinline__ float fsilu(float x) {
    return x * __builtin_amdgcn_rcpf(1.f + __builtin_amdgcn_exp2f(-LOG2E * x));
}
__device__ __forceinline__ float fsig(float x) {
    return __builtin_amdgcn_rcpf(1.f + __builtin_amdgcn_exp2f(-LOG2E * x));
}

__device__ __forceinline__ unsigned short f2bf(float x) {
    union { float f; unsigned u; } v; v.f = x;
    unsigned r = (v.u + 0x7fffu + ((v.u >> 16) & 1u)) >> 16;
    return (unsigned short)r;
}
__device__ __forceinline__ float bf2f(unsigned short s) {
    union { unsigned u; float f; } v; v.u = ((unsigned)s) << 16;
    return v.f;
}
// pack two floats to packed bf16 {lo,hi} with round-half-up
__device__ __forceinline__ unsigned pack_bf16(float lo, float hi) {
    union { float f; unsigned u; } a, b; a.f = lo; b.f = hi;
    unsigned ul = a.u + 0x8000u, uh = b.u + 0x8000u;
    return __builtin_amdgcn_perm(uh, ul, 0x07060302u);
}

// ------- pre-kernel: weight prep (64 blk) + lin x=h@W^T+b (625 blk) -------
#define PRE_PREP_BLOCKS 64
#define PRE_LIN_BLOCKS  625   // 32 nodes per block
__global__ __launch_bounds__(256) void pre_kernel(
    const float* __restrict__ w1, const float* __restrict__ w2,
    unsigned short* __restrict__ w1b, float* __restrict__ w1last,
    unsigned short* __restrict__ w2b,
    const float* __restrict__ h, const float* __restrict__ lw,
    const float* __restrict__ lb, float* __restrict__ x,
    unsigned short* __restrict__ xb) {
    __shared__ float hs[32][128];
    int b = blockIdx.x;
    int t = threadIdx.x;

    if (b < PRE_PREP_BLOCKS) {
        int i = b * 256 + t;
        const int stride = PRE_PREP_BLOCKS * 256;
        for (int idx = i; idx < 256 * 256; idx += stride) {
            int o = idx >> 8, k = idx & 255;
            w1b[idx] = f2bf(w1[o * 257 + k]);
        }
        // w2b k-order permuted: within each 32-chunk b2: pos b2+2l <- k=b2+l ; b2+2l+1 <- k=b2+16+l
        for (int idx = i; idx < 128 * 256; idx += stride) {
            int n2 = idx >> 8, p = idx & 255;
            int bb = p & ~31, off = p & 31;
            int ksrc = bb + (off >> 1) + ((off & 1) << 4);
            w2b[idx] = f2bf(w2[n2 * 256 + ksrc]);
        }
        for (int idx = i; idx < 256; idx += stride)
            w1last[idx] = w1[idx * 257 + 256];
    } else {
        int nb = b - PRE_PREP_BLOCKS;
        int n0 = nb * 32;
        int ch = t & 127, g = t >> 7;   // g in {0,1}, 16 nodes each
#pragma unroll
        for (int j = 0; j < 16; ++j) hs[g * 16 + j][ch] = h[(size_t)(n0 + g * 16 + j) * DIM + ch];
        __syncthreads();
        float acc[16];
#pragma unroll
        for (int j = 0; j < 16; ++j) acc[j] = 0.f;
        for (int kc = 0; kc < 128; kc += 4) {
            float4 wv = *(const float4*)&lw[(size_t)ch * DIM + kc];
#pragma unroll
            for (int j = 0; j < 16; ++j)
                acc[j] += wv.x * hs[g * 16 + j][kc] + wv.y * hs[g * 16 + j][kc + 1]
                        + wv.z * hs[g * 16 + j][kc + 2] + wv.w * hs[g * 16 + j][kc + 3];
        }
        float bias = lb[ch];
#pragma unroll
        for (int j = 0; j < 16; ++j) {
            float v = acc[j] + bias;
            int n = n0 + g * 16 + j;
            x[(size_t)n * DIM + ch] = v;
            xb[(size_t)n * DIM + ch] = f2bf(v);
        }
    }
}

// ---------------- Kernel 2: edge MLP -> att[E] + inline adj build ----------------
// 512 threads (8 waves), 64 edges/block; waves split N. LDS-staged indices,
// 16x16x32 both layers, packed a1 + permuted-k W2, layer3 in registers.
// The tid<64 staging threads also build the adjacency lists (atomics overlap MFMA).
__global__ __launch_bounds__(512, 4) void edge_kernel(
    const unsigned short* __restrict__ xb,
    const float* __restrict__ dist, const float* __restrict__ emask,
    const int* __restrict__ edges,
    const unsigned short* __restrict__ w1b, const float* __restrict__ w1last,
    const float* __restrict__ b1,
    const unsigned short* __restrict__ w2b, const float* __restrict__ b2,
    const float* __restrict__ w3, const float* __restrict__ b3v,
    float* __restrict__ att, int* __restrict__ cnt, int* __restrict__ adj, int E) {
    __shared__ unsigned short buf[EPB * XST];
    __shared__ float part[8][EPB];
    __shared__ float dvals[EPB];
    __shared__ int ridx[EPB], cidx[EPB];

    int tid = threadIdx.x;
    int eb = blockIdx.x * EPB;

    if (tid < EPB) {
        int e = eb + tid;
        int r = edges[e];
        ridx[tid] = r;
        cidx[tid] = edges[E + e];
        dvals[tid] = dist[e] * emask[e];
        int slot = atomicAdd(&cnt[r], 1);
        if (slot < CAP) adj[(size_t)r * CAP + slot] = e;
    }
    __syncthreads();

#pragma unroll
    for (int i = 0; i < 4; ++i) {
        int c = tid + 512 * i;
        int r = c >> 5;
        int cb = (c & 31) * 8;
        const unsigned short* src;
        if (cb < 128) src = xb + (size_t)ridx[r] * DIM + cb;
        else          src = xb + (size_t)cidx[r] * DIM + (cb - 128);
        *(bf16x8*)&buf[r * XST + cb] = *(const bf16x8*)src;
    }

    int wave = tid >> 6, lane = tid & 63;
    int lrow = lane & 15, quad = lane >> 4;
    int nb = wave * 32;

    float bias0 = b1[nb + lrow], bias1 = b1[nb + 16 + lrow];
    float wl0 = w1last[nb + lrow], wl1 = w1last[nb + 16 + lrow];
    int n2 = wave * 16 + lrow;
    float bias2 = b2[n2];
    float w3v = w3[n2];

    __syncthreads();

    // ---- layer 1: wave covers 32 of 256 N
    f32x4 z = {0.f, 0.f, 0.f, 0.f};
    f32x4 acc1[4][2];
#pragma unroll
    for (int mt = 0; mt < 4; ++mt)
#pragma unroll
        for (int nt = 0; nt < 2; ++nt) acc1[mt][nt] = z;

    for (int kk = 0; kk < 8; ++kk) {
        int ka = kk * 32 + quad * 8;
        bf16x8 a[4];
#pragma unroll
        for (int mt = 0; mt < 4; ++mt)
            a[mt] = *(bf16x8*)&buf[(mt * 16 + lrow) * XST + ka];
#pragma unroll
        for (int nt = 0; nt < 2; ++nt) {
            int n = nb + nt * 16 + lrow;
            bf16x8 bfrag = *(const bf16x8*)&w1b[(size_t)n * 256 + ka];
#pragma unroll
            for (int mt = 0; mt < 4; ++mt)
                acc1[mt][nt] = __builtin_amdgcn_mfma_f32_16x16x32_bf16(a[mt], bfrag, acc1[mt][nt], 0, 0, 0);
        }
    }
    __syncthreads();   // xcat dead; buf becomes permuted a1

    int colbase = nb + 2 * lrow;
#pragma unroll
    for (int mt = 0; mt < 4; ++mt) {
#pragma unroll
        for (int r = 0; r < 4; ++r) {
            int m = mt * 16 + quad * 4 + r;
            float dv = dvals[m];
            float v0 = fsilu(acc1[mt][0][r] + bias0 + dv * wl0);
            float v1 = fsilu(acc1[mt][1][r] + bias1 + dv * wl1);
            *(unsigned*)&buf[m * XST + colbase] = pack_bf16(v0, v1);
        }
    }
    __syncthreads();

    // ---- layer 2: wave covers 16 of 128 N2 (k-order permuted on both sides)
    f32x4 acc2[4];
#pragma unroll
    for (int mt = 0; mt < 4; ++mt) acc2[mt] = z;

    for (int kk = 0; kk < 8; ++kk) {
        int ka = kk * 32 + quad * 8;
        bf16x8 bfrag = *(const bf16x8*)&w2b[(size_t)n2 * 256 + ka];
#pragma unroll
        for (int mt = 0; mt < 4; ++mt) {
            bf16x8 a = *(bf16x8*)&buf[(mt * 16 + lrow) * XST + ka];
            acc2[mt] = __builtin_amdgcn_mfma_f32_16x16x32_bf16(a, bfrag, acc2[mt], 0, 0, 0);
        }
    }

    // ---- layer 3 in registers
    float s[4][4];
#pragma unroll
    for (int mt = 0; mt < 4; ++mt)
#pragma unroll
        for (int r = 0; r < 4; ++r)
            s[mt][r] = fsilu(acc2[mt][r] + bias2) * w3v;
#pragma unroll
    for (int off = 1; off < 16; off <<= 1) {
#pragma unroll
        for (int mt = 0; mt < 4; ++mt)
#pragma unroll
            for (int r = 0; r < 4; ++r)
                s[mt][r] += __shfl_xor(s[mt][r], off);
    }
    if (lrow == 0) {
#pragma unroll
        for (int mt = 0; mt < 4; ++mt)
#pragma unroll
            for (int r = 0; r < 4; ++r)
                part[wave][mt * 16 + quad * 4 + r] = s[mt][r];
    }
    __syncthreads();

    if (tid < EPB) {
        float ssum = b3v[0];
#pragma unroll
        for (int w = 0; w < 8; ++w) ssum += part[w][tid];
        att[eb + tid] = fsig(ssum) * emask[eb + tid];
    }
}

// ---------------- Kernel 4: aggregate + node MLP + LNs ----------------
// 256 threads, 8 nodes/block. Parallel staging (32 lanes per node), quarter-wave
// gather with 4 independent u32 channel-pair load chains, LDS partials, fused MLP.
__global__ __launch_bounds__(256) void node_kernel(
    const float* __restrict__ attv, const int* __restrict__ adj, const int* __restrict__ cnt,
    const int* __restrict__ edges, const unsigned short* __restrict__ xb,
    const float* __restrict__ x,
    const float* __restrict__ w1, const float* __restrict__ bb1,
    const float* __restrict__ lng, const float* __restrict__ lnb,
    const float* __restrict__ w2, const float* __restrict__ bb2,
    const float* __restrict__ gF, const float* __restrict__ bF,
    float* __restrict__ out, int E) {
    __shared__ float atts[NPB][CAP];
    __shared__ int   cols[NPB][CAP];
    __shared__ float parts[4][NPB][128];
    __shared__ float outv[NPB][128];
    __shared__ float bufs[NPB][128];
    __shared__ float mu_s[NPB], rs_s[NPB];
    __shared__ int cnts[NPB];

    int t = threadIdx.x;
    int n0 = blockIdx.x * NPB;

    if (t < NPB) { int c = cnt[n0 + t]; cnts[t] = c > CAP ? CAP : c; }
    __syncthreads();

    // stage lists: group jg = t>>5 (8 groups of 32 lanes), one node each, one pass
    {
        int jg = t >> 5, l = t & 31;
        int c = cnts[jg];
        const int* al = adj + (size_t)(n0 + jg) * CAP;
        for (int i = l; i < c; i += 32) {
            int e = al[i];
            atts[jg][i] = attv[e];
            cols[jg][i] = edges[E + e];
        }
    }
    __syncthreads();

    // gather partial sums: quarter q of channels, edges i === q (mod 4), 4 chains
    int q = t >> 6, cp = t & 63;
#pragma unroll 1
    for (int j = 0; j < NPB; ++j) {
        int c = cnts[j];
        float lo0 = 0.f, hi0 = 0.f, lo1 = 0.f, hi1 = 0.f;
        float lo2 = 0.f, hi2 = 0.f, lo3 = 0.f, hi3 = 0.f;
        int i = q;
        for (; i + 12 < c; i += 16) {
            unsigned u0 = *(const unsigned*)&xb[(size_t)cols[j][i]      * DIM + cp * 2];
            unsigned u1 = *(const unsigned*)&xb[(size_t)cols[j][i + 4]  * DIM + cp * 2];
            unsigned u2 = *(const unsigned*)&xb[(size_t)cols[j][i + 8]  * DIM + cp * 2];
            unsigned u3 = *(const unsigned*)&xb[(size_t)cols[j][i + 12] * DIM + cp * 2];
            float w0 = atts[j][i], w1v = atts[j][i + 4], w2v = atts[j][i + 8], w3v = atts[j][i + 12];
            lo0 += w0 * bf2f((unsigned short)(u0 & 0xffff)); hi0 += w0 * bf2f((unsigned short)(u0 >> 16));
            lo1 += w1v * bf2f((unsigned short)(u1 & 0xffff)); hi1 += w1v * bf2f((unsigned short)(u1 >> 16));
            lo2 += w2v * bf2f((unsigned short)(u2 & 0xffff)); hi2 += w2v * bf2f((unsigned short)(u2 >> 16));
            lo3 += w3v * bf2f((unsigned short)(u3 & 0xffff)); hi3 += w3v * bf2f((unsigned short)(u3 >> 16));
        }
        for (; i < c; i += 4) {
            unsigned u0 = *(const unsigned*)&xb[(size_t)cols[j][i] * DIM + cp * 2];
            float w0 = atts[j][i];
            lo0 += w0 * bf2f((unsigned short)(u0 & 0xffff));
            hi0 += w0 * bf2f((unsigned short)(u0 >> 16));
        }
        parts[q][j][cp * 2]     = (lo0 + lo1) + (lo2 + lo3);
        parts[q][j][cp * 2 + 1] = (hi0 + hi1) + (hi2 + hi3);
    }
    __syncthreads();

    // combine + node MLP: thread (h = t>>7, ch = t&127) owns nodes h*4..h*4+3
    int h = t >> 7, ch = t & 127;
    float xres[4];
#pragma unroll
    for (int jj = 0; jj < 4; ++jj) {
        int j = h * 4 + jj;
        outv[j][ch] = (parts[0][j][ch] + parts[1][j][ch] + parts[2][j][ch] + parts[3][j][ch]) * 0.01f;
        xres[jj] = x[(size_t)(n0 + j) * DIM + ch];
    }
    __syncthreads();

    float a1[4] = {0, 0, 0, 0};
    for (int kc = 0; kc < 128; kc += 4) {
        float4 wv = *(const float4*)&w1[(size_t)ch * DIM + kc];
#pragma unroll
        for (int jj = 0; jj < 4; ++jj) {
            int j = h * 4 + jj;
            a1[jj] += wv.x * outv[j][kc] + wv.y * outv[j][kc + 1] + wv.z * outv[j][kc + 2] + wv.w * outv[j][kc + 3];
        }
    }
    float bias1 = bb1[ch];
#pragma unroll
    for (int jj = 0; jj < 4; ++jj) bufs[h * 4 + jj][ch] = a1[jj] + bias1;
    __syncthreads();

    // LN reduction 1: 8 groups of 32 lanes
    {
        int j = t >> 5, l = t & 31;
        float s = 0.f, qq = 0.f;
#pragma unroll
        for (int i = 0; i < 4; ++i) { float v = bufs[j][l + 32 * i]; s += v; qq += v * v; }
#pragma unroll
        for (int off = 16; off; off >>= 1) { s += __shfl_xor(s, off); qq += __shfl_xor(qq, off); }
        if (l == 0) {
            float mu = s * (1.f / 128.f);
            float var = qq * (1.f / 128.f) - mu * mu;
            mu_s[j] = mu; rs_s[j] = __builtin_amdgcn_rsqf(var + 1e-5f);
        }
    }
    __syncthreads();

    float g = lng[ch], bb = lnb[ch];
    float h2[4];
#pragma unroll
    for (int jj = 0; jj < 4; ++jj) {
        int j = h * 4 + jj;
        h2[jj] = fsilu((bufs[j][ch] - mu_s[j]) * rs_s[j] * g + bb);
    }
    __syncthreads();
#pragma unroll
    for (int jj = 0; jj < 4; ++jj) bufs[h * 4 + jj][ch] = h2[jj];
    __syncthreads();

    float a3[4] = {0, 0, 0, 0};
    for (int kc = 0; kc < 128; kc += 4) {
        float4 wv = *(const float4*)&w2[(size_t)ch * DIM + kc];
#pragma unroll
        for (int jj = 0; jj < 4; ++jj) {
            int j = h * 4 + jj;
            a3[jj] += wv.x * bufs[j][kc] + wv.y * bufs[j][kc + 1] + wv.z * bufs[j][kc + 2] + wv.w * bufs[j][kc + 3];
        }
    }
    float bias2 = bb2[ch];
    float hh[4];
#pragma unroll
    for (int jj = 0; jj < 4; ++jj) hh[jj] = a3[jj] + bias2 + xres[jj];
    __syncthreads();
#pragma unroll
    for (int jj = 0; jj < 4; ++jj) bufs[h * 4 + jj][ch] = hh[jj];
    __syncthreads();

    // LN reduction 2
    {
        int j = t >> 5, l = t & 31;
        float s = 0.f, qq = 0.f;
#pragma unroll
        for (int i = 0; i < 4; ++i) { float v = bufs[j][l + 32 * i]; s += v; qq += v * v; }
#pragma unroll
        for (int off = 16; off; off >>= 1) { s += __shfl_xor(s, off); qq += __shfl_xor(qq, off); }
        if (l == 0) {
            float mu = s * (1.f / 128.f);
            float var = qq * (1.f / 128.f) - mu * mu;
            mu_s[j] = mu; rs_s[j] = __builtin_amdgcn_rsqf(var + 1e-5f);
        }
    }
    __syncthreads();

    float gf = gF[ch], bf = bF[ch];
#pragma unroll
    for (int jj = 0; jj < 4; ++jj) {
        int j = h * 4 + jj;
        float y = (hh[jj] - mu_s[j]) * rs_s[j] * gf + bf;
        out[(size_t)(n0 + j) * DIM + ch] = fsilu(y);
    }
}

extern "C" void kernel_launch(void* const* d_in, const int* in_sizes, int n_in,
                              void* d_out, int out_size, void* d_ws, size_t ws_size,
                              hipStream_t stream) {
    const float* h         = (const float*)d_in[0];
    const float* distances = (const float*)d_in[1];
    const float* edge_mask = (const float*)d_in[3];
    const float* lin_w     = (const float*)d_in[4];
    const float* lin_b     = (const float*)d_in[5];
    const float* att_w1    = (const float*)d_in[6];
    const float* att_b1    = (const float*)d_in[7];
    const float* att_w2    = (const float*)d_in[8];
    const float* att_b2    = (const float*)d_in[9];
    const float* att_w3    = (const float*)d_in[10];
    const float* att_b3    = (const float*)d_in[11];
    const float* nm_w1     = (const float*)d_in[12];
    const float* nm_b1     = (const float*)d_in[13];
    const float* nm_ln_g   = (const float*)d_in[14];
    const float* nm_ln_b   = (const float*)d_in[15];
    const float* nm_w2     = (const float*)d_in[16];
    const float* nm_b2     = (const float*)d_in[17];
    const float* ln_g      = (const float*)d_in[18];
    const float* ln_b      = (const float*)d_in[19];
    const int*   edges     = (const int*)d_in[20];
    float* out = (float*)d_out;

    const int N = N_NODES, E = E_EDGES;

    char* ws = (char*)d_ws;
    float* x            = (float*)ws;            ws += (size_t)N * DIM * 4;
    unsigned short* xb  = (unsigned short*)ws;   ws += (size_t)N * DIM * 2;
    float* attv         = (float*)ws;            ws += (size_t)E * 4;
    int* cnt            = (int*)ws;              ws += (size_t)N * 4;
    int* adj            = (int*)ws;              ws += (size_t)N * CAP * 4;
    unsigned short* w1b = (unsigned short*)ws;   ws += 256 * 256 * 2;
    float* w1last       = (float*)ws;            ws += 256 * 4;
    unsigned short* w2b = (unsigned short*)ws;   ws += 128 * 256 * 2;

    hipMemsetAsync(cnt, 0, (size_t)N * 4, stream);

    pre_kernel<<<PRE_PREP_BLOCKS + PRE_LIN_BLOCKS, 256, 0, stream>>>(
        att_w1, att_w2, w1b, w1last, w2b,
        h, lin_w, lin_b, x, xb);
    edge_kernel<<<E / EPB, 512, 0, stream>>>(xb, distances, edge_mask, edges,
                                             w1b, w1last, att_b1, w2b, att_b2,
                                             att_w3, att_b3, attv, cnt, adj, E);
    node_kernel<<<N / NPB, 256, 0, stream>>>(attv, adj, cnt, edges, xb, x,
                                             nm_w1, nm_b1, nm_ln_g, nm_ln_b,
                                             nm_w2, nm_b2, ln_g, ln_b, out, E);
}

// Round 9
// 497.701 us; speedup vs baseline: 1.0703x; 1.0703x over previous
//
#include <hip/hip_runtime.h>
#include <hip/hip_bf16.h>

#define N_NODES 20000
#define E_EDGES 640000
#define DIM 128
#define CAP 96    // Poisson(32) max degree ~65; 96 is >10-sigma safe
#define EPB 64    // edges per block in edge_kernel
#define NPB 8     // nodes per block in node_kernel
#define XST 264   // padded ushort stride for [64][256] LDS tile

typedef __attribute__((ext_vector_type(8))) short bf16x8;
typedef __attribute__((ext_vector_type(4))) float f32x4;

#define LOG2E 1.44269504f
__device__ __forceinline__ float fsilu(float x) {
    return x * __builtin_amdgcn_rcpf(1.f + __builtin_amdgcn_exp2f(-LOG2E * x));
}
__device__ __forceinline__ float fsig(float x) {
    return __builtin_amdgcn_rcpf(1.f + __builtin_amdgcn_exp2f(-LOG2E * x));
}

__device__ __forceinline__ unsigned short f2bf(float x) {
    union { float f; unsigned u; } v; v.f = x;
    unsigned r = (v.u + 0x7fffu + ((v.u >> 16) & 1u)) >> 16;
    return (unsigned short)r;
}
__device__ __forceinline__ float bf2f(unsigned short s) {
    union { unsigned u; float f; } v; v.u = ((unsigned)s) << 16;
    return v.f;
}
// pack two floats to packed bf16 {lo,hi} with round-half-up
__device__ __forceinline__ unsigned pack_bf16(float lo, float hi) {
    union { float f; unsigned u; } a, b; a.f = lo; b.f = hi;
    unsigned ul = a.u + 0x8000u, uh = b.u + 0x8000u;
    return __builtin_amdgcn_perm(uh, ul, 0x07060302u);
}

// ------- fused pre-kernel: weight prep (64) + lin (625) + adj build (2500) -------
// adj2 stores {edge id, col} per slot: the col copy is free (write-allocate is
// per-64B-line) and removes one random load from node staging.
#define PRE_PREP_BLOCKS 64
#define PRE_LIN_BLOCKS  625   // 32 nodes per block
#define PRE_ADJ_BLOCKS  2500
__global__ __launch_bounds__(256) void pre_kernel(
    const float* __restrict__ w1, const float* __restrict__ w2,
    unsigned short* __restrict__ w1b, float* __restrict__ w1last,
    unsigned short* __restrict__ w2b,
    const float* __restrict__ h, const float* __restrict__ lw,
    const float* __restrict__ lb, float* __restrict__ x,
    unsigned short* __restrict__ xb,
    const int* __restrict__ edges, int* __restrict__ cnt,
    int2* __restrict__ adj2, int E) {
    __shared__ float hs[32][128];
    int b = blockIdx.x;
    int t = threadIdx.x;

    if (b < PRE_PREP_BLOCKS) {
        int i = b * 256 + t;
        const int stride = PRE_PREP_BLOCKS * 256;
        for (int idx = i; idx < 256 * 256; idx += stride) {
            int o = idx >> 8, k = idx & 255;
            w1b[idx] = f2bf(w1[o * 257 + k]);
        }
        // w2b k-order permuted: within each 32-chunk b2: pos b2+2l <- k=b2+l ; b2+2l+1 <- k=b2+16+l
        for (int idx = i; idx < 128 * 256; idx += stride) {
            int n2 = idx >> 8, p = idx & 255;
            int bb = p & ~31, off = p & 31;
            int ksrc = bb + (off >> 1) + ((off & 1) << 4);
            w2b[idx] = f2bf(w2[n2 * 256 + ksrc]);
        }
        for (int idx = i; idx < 256; idx += stride)
            w1last[idx] = w1[idx * 257 + 256];
    } else if (b < PRE_PREP_BLOCKS + PRE_LIN_BLOCKS) {
        int nb = b - PRE_PREP_BLOCKS;
        int n0 = nb * 32;
        int ch = t & 127, g = t >> 7;   // g in {0,1}, 16 nodes each
#pragma unroll
        for (int j = 0; j < 16; ++j) hs[g * 16 + j][ch] = h[(size_t)(n0 + g * 16 + j) * DIM + ch];
        __syncthreads();
        float acc[16];
#pragma unroll
        for (int j = 0; j < 16; ++j) acc[j] = 0.f;
        for (int kc = 0; kc < 128; kc += 4) {
            float4 wv = *(const float4*)&lw[(size_t)ch * DIM + kc];
#pragma unroll
            for (int j = 0; j < 16; ++j)
                acc[j] += wv.x * hs[g * 16 + j][kc] + wv.y * hs[g * 16 + j][kc + 1]
                        + wv.z * hs[g * 16 + j][kc + 2] + wv.w * hs[g * 16 + j][kc + 3];
        }
        float bias = lb[ch];
#pragma unroll
        for (int j = 0; j < 16; ++j) {
            float v = acc[j] + bias;
            int n = n0 + g * 16 + j;
            x[(size_t)n * DIM + ch] = v;
            xb[(size_t)n * DIM + ch] = f2bf(v);
        }
    } else {
        int e = (b - PRE_PREP_BLOCKS - PRE_LIN_BLOCKS) * 256 + t;
        if (e < E) {
            int r = edges[e];
            int col = edges[E + e];
            int slot = atomicAdd(&cnt[r], 1);
            if (slot < CAP) { int2 v; v.x = e; v.y = col; adj2[(size_t)r * CAP + slot] = v; }
        }
    }
}

// ---------------- Kernel 2: edge MLP -> att[E] (R7 structure, frozen) ----------------
// 512 threads (8 waves), 64 edges/block; waves split N. LDS-staged indices,
// 16x16x32 both layers, packed a1 + permuted-k W2, layer3 in registers.
__global__ __launch_bounds__(512, 4) void edge_kernel(
    const unsigned short* __restrict__ xb,
    const float* __restrict__ dist, const float* __restrict__ emask,
    const int* __restrict__ edges,
    const unsigned short* __restrict__ w1b, const float* __restrict__ w1last,
    const float* __restrict__ b1,
    const unsigned short* __restrict__ w2b, const float* __restrict__ b2,
    const float* __restrict__ w3, const float* __restrict__ b3v,
    float* __restrict__ att, int E) {
    __shared__ unsigned short buf[EPB * XST];
    __shared__ float part[8][EPB];
    __shared__ float dvals[EPB];
    __shared__ int ridx[EPB], cidx[EPB];

    int tid = threadIdx.x;
    int eb = blockIdx.x * EPB;

    if (tid < EPB) {
        int e = eb + tid;
        ridx[tid] = edges[e];
        cidx[tid] = edges[E + e];
        dvals[tid] = dist[e] * emask[e];
    }
    __syncthreads();

#pragma unroll
    for (int i = 0; i < 4; ++i) {
        int c = tid + 512 * i;
        int r = c >> 5;
        int cb = (c & 31) * 8;
        const unsigned short* src;
        if (cb < 128) src = xb + (size_t)ridx[r] * DIM + cb;
        else          src = xb + (size_t)cidx[r] * DIM + (cb - 128);
        *(bf16x8*)&buf[r * XST + cb] = *(const bf16x8*)src;
    }

    int wave = tid >> 6, lane = tid & 63;
    int lrow = lane & 15, quad = lane >> 4;
    int nb = wave * 32;

    float bias0 = b1[nb + lrow], bias1 = b1[nb + 16 + lrow];
    float wl0 = w1last[nb + lrow], wl1 = w1last[nb + 16 + lrow];
    int n2 = wave * 16 + lrow;
    float bias2 = b2[n2];
    float w3v = w3[n2];

    __syncthreads();

    // ---- layer 1: wave covers 32 of 256 N
    f32x4 z = {0.f, 0.f, 0.f, 0.f};
    f32x4 acc1[4][2];
#pragma unroll
    for (int mt = 0; mt < 4; ++mt)
#pragma unroll
        for (int nt = 0; nt < 2; ++nt) acc1[mt][nt] = z;

    for (int kk = 0; kk < 8; ++kk) {
        int ka = kk * 32 + quad * 8;
        bf16x8 a[4];
#pragma unroll
        for (int mt = 0; mt < 4; ++mt)
            a[mt] = *(bf16x8*)&buf[(mt * 16 + lrow) * XST + ka];
#pragma unroll
        for (int nt = 0; nt < 2; ++nt) {
            int n = nb + nt * 16 + lrow;
            bf16x8 bfrag = *(const bf16x8*)&w1b[(size_t)n * 256 + ka];
#pragma unroll
            for (int mt = 0; mt < 4; ++mt)
                acc1[mt][nt] = __builtin_amdgcn_mfma_f32_16x16x32_bf16(a[mt], bfrag, acc1[mt][nt], 0, 0, 0);
        }
    }
    __syncthreads();   // xcat dead; buf becomes permuted a1

    int colbase = nb + 2 * lrow;
#pragma unroll
    for (int mt = 0; mt < 4; ++mt) {
#pragma unroll
        for (int r = 0; r < 4; ++r) {
            int m = mt * 16 + quad * 4 + r;
            float dv = dvals[m];
            float v0 = fsilu(acc1[mt][0][r] + bias0 + dv * wl0);
            float v1 = fsilu(acc1[mt][1][r] + bias1 + dv * wl1);
            *(unsigned*)&buf[m * XST + colbase] = pack_bf16(v0, v1);
        }
    }
    __syncthreads();

    // ---- layer 2: wave covers 16 of 128 N2 (k-order permuted on both sides)
    f32x4 acc2[4];
#pragma unroll
    for (int mt = 0; mt < 4; ++mt) acc2[mt] = z;

    for (int kk = 0; kk < 8; ++kk) {
        int ka = kk * 32 + quad * 8;
        bf16x8 bfrag = *(const bf16x8*)&w2b[(size_t)n2 * 256 + ka];
#pragma unroll
        for (int mt = 0; mt < 4; ++mt) {
            bf16x8 a = *(bf16x8*)&buf[(mt * 16 + lrow) * XST + ka];
            acc2[mt] = __builtin_amdgcn_mfma_f32_16x16x32_bf16(a, bfrag, acc2[mt], 0, 0, 0);
        }
    }

    // ---- layer 3 in registers
    float s[4][4];
#pragma unroll
    for (int mt = 0; mt < 4; ++mt)
#pragma unroll
        for (int r = 0; r < 4; ++r)
            s[mt][r] = fsilu(acc2[mt][r] + bias2) * w3v;
#pragma unroll
    for (int off = 1; off < 16; off <<= 1) {
#pragma unroll
        for (int mt = 0; mt < 4; ++mt)
#pragma unroll
            for (int r = 0; r < 4; ++r)
                s[mt][r] += __shfl_xor(s[mt][r], off);
    }
    if (lrow == 0) {
#pragma unroll
        for (int mt = 0; mt < 4; ++mt)
#pragma unroll
            for (int r = 0; r < 4; ++r)
                part[wave][mt * 16 + quad * 4 + r] = s[mt][r];
    }
    __syncthreads();

    if (tid < EPB) {
        float ssum = b3v[0];
#pragma unroll
        for (int w = 0; w < 8; ++w) ssum += part[w][tid];
        att[eb + tid] = fsig(ssum) * emask[eb + tid];
    }
}

// ---------------- Kernel 4: aggregate + node MLP + LNs ----------------
// 256 threads, 8 nodes/block. int2 staging (coalesced col, one random attv load),
// quarter-wave gather with 4 independent u32 channel-pair chains, fused MLP.
__global__ __launch_bounds__(256) void node_kernel(
    const float* __restrict__ attv, const int2* __restrict__ adj2, const int* __restrict__ cnt,
    const unsigned short* __restrict__ xb,
    const float* __restrict__ x,
    const float* __restrict__ w1, const float* __restrict__ bb1,
    const float* __restrict__ lng, const float* __restrict__ lnb,
    const float* __restrict__ w2, const float* __restrict__ bb2,
    const float* __restrict__ gF, const float* __restrict__ bF,
    float* __restrict__ out, int E) {
    __shared__ float atts[NPB][CAP];
    __shared__ int   cols[NPB][CAP];
    __shared__ float parts[4][NPB][128];
    __shared__ float outv[NPB][128];
    __shared__ float bufs[NPB][128];
    __shared__ float mu_s[NPB], rs_s[NPB];
    __shared__ int cnts[NPB];

    int t = threadIdx.x;
    int n0 = blockIdx.x * NPB;

    if (t < NPB) { int c = cnt[n0 + t]; cnts[t] = c > CAP ? CAP : c; }
    __syncthreads();

    // stage lists: group jg = t>>5 (8 groups of 32 lanes), one node each, one pass
    {
        int jg = t >> 5, l = t & 31;
        int c = cnts[jg];
        const int2* al = adj2 + (size_t)(n0 + jg) * CAP;
        for (int i = l; i < c; i += 32) {
            int2 v = al[i];
            atts[jg][i] = attv[v.x];
            cols[jg][i] = v.y;
        }
    }
    __syncthreads();

    // gather partial sums: quarter q of channels, edges i === q (mod 4), 4 chains
    int q = t >> 6, cp = t & 63;
#pragma unroll 1
    for (int j = 0; j < NPB; ++j) {
        int c = cnts[j];
        float lo0 = 0.f, hi0 = 0.f, lo1 = 0.f, hi1 = 0.f;
        float lo2 = 0.f, hi2 = 0.f, lo3 = 0.f, hi3 = 0.f;
        int i = q;
        for (; i + 12 < c; i += 16) {
            unsigned u0 = *(const unsigned*)&xb[(size_t)cols[j][i]      * DIM + cp * 2];
            unsigned u1 = *(const unsigned*)&xb[(size_t)cols[j][i + 4]  * DIM + cp * 2];
            unsigned u2 = *(const unsigned*)&xb[(size_t)cols[j][i + 8]  * DIM + cp * 2];
            unsigned u3 = *(const unsigned*)&xb[(size_t)cols[j][i + 12] * DIM + cp * 2];
            float w0 = atts[j][i], w1v = atts[j][i + 4], w2v = atts[j][i + 8], w3v = atts[j][i + 12];
            lo0 += w0 * bf2f((unsigned short)(u0 & 0xffff)); hi0 += w0 * bf2f((unsigned short)(u0 >> 16));
            lo1 += w1v * bf2f((unsigned short)(u1 & 0xffff)); hi1 += w1v * bf2f((unsigned short)(u1 >> 16));
            lo2 += w2v * bf2f((unsigned short)(u2 & 0xffff)); hi2 += w2v * bf2f((unsigned short)(u2 >> 16));
            lo3 += w3v * bf2f((unsigned short)(u3 & 0xffff)); hi3 += w3v * bf2f((unsigned short)(u3 >> 16));
        }
        for (; i < c; i += 4) {
            unsigned u0 = *(const unsigned*)&xb[(size_t)cols[j][i] * DIM + cp * 2];
            float w0 = atts[j][i];
            lo0 += w0 * bf2f((unsigned short)(u0 & 0xffff));
            hi0 += w0 * bf2f((unsigned short)(u0 >> 16));
        }
        parts[q][j][cp * 2]     = (lo0 + lo1) + (lo2 + lo3);
        parts[q][j][cp * 2 + 1] = (hi0 + hi1) + (hi2 + hi3);
    }
    __syncthreads();

    // combine + node MLP: thread (h = t>>7, ch = t&127) owns nodes h*4..h*4+3
    int h = t >> 7, ch = t & 127;
    float xres[4];
#pragma unroll
    for (int jj = 0; jj < 4; ++jj) {
        int j = h * 4 + jj;
        outv[j][ch] = (parts[0][j][ch] + parts[1][j][ch] + parts[2][j][ch] + parts[3][j][ch]) * 0.01f;
        xres[jj] = x[(size_t)(n0 + j) * DIM + ch];
    }
    __syncthreads();

    float a1[4] = {0, 0, 0, 0};
    for (int kc = 0; kc < 128; kc += 4) {
        float4 wv = *(const float4*)&w1[(size_t)ch * DIM + kc];
#pragma unroll
        for (int jj = 0; jj < 4; ++jj) {
            int j = h * 4 + jj;
            a1[jj] += wv.x * outv[j][kc] + wv.y * outv[j][kc + 1] + wv.z * outv[j][kc + 2] + wv.w * outv[j][kc + 3];
        }
    }
    float bias1 = bb1[ch];
#pragma unroll
    for (int jj = 0; jj < 4; ++jj) bufs[h * 4 + jj][ch] = a1[jj] + bias1;
    __syncthreads();

    // LN reduction 1: 8 groups of 32 lanes
    {
        int j = t >> 5, l = t & 31;
        float s = 0.f, qq = 0.f;
#pragma unroll
        for (int i = 0; i < 4; ++i) { float v = bufs[j][l + 32 * i]; s += v; qq += v * v; }
#pragma unroll
        for (int off = 16; off; off >>= 1) { s += __shfl_xor(s, off); qq += __shfl_xor(qq, off); }
        if (l == 0) {
            float mu = s * (1.f / 128.f);
            float var = qq * (1.f / 128.f) - mu * mu;
            mu_s[j] = mu; rs_s[j] = __builtin_amdgcn_rsqf(var + 1e-5f);
        }
    }
    __syncthreads();

    float g = lng[ch], bb = lnb[ch];
    float h2[4];
#pragma unroll
    for (int jj = 0; jj < 4; ++jj) {
        int j = h * 4 + jj;
        h2[jj] = fsilu((bufs[j][ch] - mu_s[j]) * rs_s[j] * g + bb);
    }
    __syncthreads();
#pragma unroll
    for (int jj = 0; jj < 4; ++jj) bufs[h * 4 + jj][ch] = h2[jj];
    __syncthreads();

    float a3[4] = {0, 0, 0, 0};
    for (int kc = 0; kc < 128; kc += 4) {
        float4 wv = *(const float4*)&w2[(size_t)ch * DIM + kc];
#pragma unroll
        for (int jj = 0; jj < 4; ++jj) {
            int j = h * 4 + jj;
            a3[jj] += wv.x * bufs[j][kc] + wv.y * bufs[j][kc + 1] + wv.z * bufs[j][kc + 2] + wv.w * bufs[j][kc + 3];
        }
    }
    float bias2 = bb2[ch];
    float hh[4];
#pragma unroll
    for (int jj = 0; jj < 4; ++jj) hh[jj] = a3[jj] + bias2 + xres[jj];
    __syncthreads();
#pragma unroll
    for (int jj = 0; jj < 4; ++jj) bufs[h * 4 + jj][ch] = hh[jj];
    __syncthreads();

    // LN reduction 2
    {
        int j = t >> 5, l = t & 31;
        float s = 0.f, qq = 0.f;
#pragma unroll
        for (int i = 0; i < 4; ++i) { float v = bufs[j][l + 32 * i]; s += v; qq += v * v; }
#pragma unroll
        for (int off = 16; off; off >>= 1) { s += __shfl_xor(s, off); qq += __shfl_xor(qq, off); }
        if (l == 0) {
            float mu = s * (1.f / 128.f);
            float var = qq * (1.f / 128.f) - mu * mu;
            mu_s[j] = mu; rs_s[j] = __builtin_amdgcn_rsqf(var + 1e-5f);
        }
    }
    __syncthreads();

    float gf = gF[ch], bf = bF[ch];
#pragma unroll
    for (int jj = 0; jj < 4; ++jj) {
        int j = h * 4 + jj;
        float y = (hh[jj] - mu_s[j]) * rs_s[j] * gf + bf;
        out[(size_t)(n0 + j) * DIM + ch] = fsilu(y);
    }
}

extern "C" void kernel_launch(void* const* d_in, const int* in_sizes, int n_in,
                              void* d_out, int out_size, void* d_ws, size_t ws_size,
                              hipStream_t stream) {
    const float* h         = (const float*)d_in[0];
    const float* distances = (const float*)d_in[1];
    const float* edge_mask = (const float*)d_in[3];
    const float* lin_w     = (const float*)d_in[4];
    const float* lin_b     = (const float*)d_in[5];
    const float* att_w1    = (const float*)d_in[6];
    const float* att_b1    = (const float*)d_in[7];
    const float* att_w2    = (const float*)d_in[8];
    const float* att_b2    = (const float*)d_in[9];
    const float* att_w3    = (const float*)d_in[10];
    const float* att_b3    = (const float*)d_in[11];
    const float* nm_w1     = (const float*)d_in[12];
    const float* nm_b1     = (const float*)d_in[13];
    const float* nm_ln_g   = (const float*)d_in[14];
    const float* nm_ln_b   = (const float*)d_in[15];
    const float* nm_w2     = (const float*)d_in[16];
    const float* nm_b2     = (const float*)d_in[17];
    const float* ln_g      = (const float*)d_in[18];
    const float* ln_b      = (const float*)d_in[19];
    const int*   edges     = (const int*)d_in[20];
    float* out = (float*)d_out;

    const int N = N_NODES, E = E_EDGES;

    char* ws = (char*)d_ws;
    float* x            = (float*)ws;            ws += (size_t)N * DIM * 4;
    unsigned short* xb  = (unsigned short*)ws;   ws += (size_t)N * DIM * 2;
    float* attv         = (float*)ws;            ws += (size_t)E * 4;
    int* cnt            = (int*)ws;              ws += (size_t)N * 4;
    int2* adj2          = (int2*)ws;             ws += (size_t)N * CAP * 8;
    unsigned short* w1b = (unsigned short*)ws;   ws += 256 * 256 * 2;
    float* w1last       = (float*)ws;            ws += 256 * 4;
    unsigned short* w2b = (unsigned short*)ws;   ws += 128 * 256 * 2;

    hipMemsetAsync(cnt, 0, (size_t)N * 4, stream);

    pre_kernel<<<PRE_PREP_BLOCKS + PRE_LIN_BLOCKS + PRE_ADJ_BLOCKS, 256, 0, stream>>>(
        att_w1, att_w2, w1b, w1last, w2b,
        h, lin_w, lin_b, x, xb,
        edges, cnt, adj2, E);
    edge_kernel<<<E / EPB, 512, 0, stream>>>(xb, distances, edge_mask, edges,
                                             w1b, w1last, att_b1, w2b, att_b2,
                                             att_w3, att_b3, attv, E);
    node_kernel<<<N / NPB, 256, 0, stream>>>(attv, adj2, cnt, xb, x,
                                             nm_w1, nm_b1, nm_ln_g, nm_ln_b,
                                             nm_w2, nm_b2, ln_g, ln_b, out, E);
}

// Round 10
// 490.359 us; speedup vs baseline: 1.0864x; 1.0150x over previous
//
#include <hip/hip_runtime.h>
#include <hip/hip_bf16.h>

#define N_NODES 20000
#define E_EDGES 640000
#define DIM 128
#define CAP 96    // Poisson(32) max degree ~65; 96 is >10-sigma safe
#define EPB 64    // edges per block in edge_kernel
#define NPB 8     // nodes per block in node_kernel
#define XST 264   // padded ushort stride for [64][256] LDS tile

typedef __attribute__((ext_vector_type(8))) short bf16x8;
typedef __attribute__((ext_vector_type(4))) float f32x4;

#define LOG2E 1.44269504f
__device__ __forceinline__ float fsilu(float x) {
    return x * __builtin_amdgcn_rcpf(1.f + __builtin_amdgcn_exp2f(-LOG2E * x));
}
__device__ __forceinline__ float fsig(float x) {
    return __builtin_amdgcn_rcpf(1.f + __builtin_amdgcn_exp2f(-LOG2E * x));
}

__device__ __forceinline__ unsigned short f2bf(float x) {
    union { float f; unsigned u; } v; v.f = x;
    unsigned r = (v.u + 0x7fffu + ((v.u >> 16) & 1u)) >> 16;
    return (unsigned short)r;
}
__device__ __forceinline__ float bf2f(unsigned short s) {
    union { unsigned u; float f; } v; v.u = ((unsigned)s) << 16;
    return v.f;
}
// pack two floats to packed bf16 {lo,hi} with round-half-up
__device__ __forceinline__ unsigned pack_bf16(float lo, float hi) {
    union { float f; unsigned u; } a, b; a.f = lo; b.f = hi;
    unsigned ul = a.u + 0x8000u, uh = b.u + 0x8000u;
    return __builtin_amdgcn_perm(uh, ul, 0x07060302u);
}

// ------- fused pre-kernel: weight prep (64) + lin (625) + adj build (2500) -------
#define PRE_PREP_BLOCKS 64
#define PRE_LIN_BLOCKS  625   // 32 nodes per block
#define PRE_ADJ_BLOCKS  2500
__global__ __launch_bounds__(256) void pre_kernel(
    const float* __restrict__ w1, const float* __restrict__ w2,
    unsigned short* __restrict__ w1b, float* __restrict__ w1last,
    unsigned short* __restrict__ w2b,
    const float* __restrict__ h, const float* __restrict__ lw,
    const float* __restrict__ lb, float* __restrict__ x,
    unsigned short* __restrict__ xb,
    const int* __restrict__ edges, int* __restrict__ cnt,
    int2* __restrict__ adj2, int E) {
    __shared__ float hs[32][128];
    int b = blockIdx.x;
    int t = threadIdx.x;

    if (b < PRE_PREP_BLOCKS) {
        int i = b * 256 + t;
        const int stride = PRE_PREP_BLOCKS * 256;
        for (int idx = i; idx < 256 * 256; idx += stride) {
            int o = idx >> 8, k = idx & 255;
            w1b[idx] = f2bf(w1[o * 257 + k]);
        }
        // w2b k-order permuted: within each 32-chunk b2: pos b2+2l <- k=b2+l ; b2+2l+1 <- k=b2+16+l
        for (int idx = i; idx < 128 * 256; idx += stride) {
            int n2 = idx >> 8, p = idx & 255;
            int bb = p & ~31, off = p & 31;
            int ksrc = bb + (off >> 1) + ((off & 1) << 4);
            w2b[idx] = f2bf(w2[n2 * 256 + ksrc]);
        }
        for (int idx = i; idx < 256; idx += stride)
            w1last[idx] = w1[idx * 257 + 256];
    } else if (b < PRE_PREP_BLOCKS + PRE_LIN_BLOCKS) {
        int nb = b - PRE_PREP_BLOCKS;
        int n0 = nb * 32;
        int ch = t & 127, g = t >> 7;   // g in {0,1}, 16 nodes each
#pragma unroll
        for (int j = 0; j < 16; ++j) hs[g * 16 + j][ch] = h[(size_t)(n0 + g * 16 + j) * DIM + ch];
        __syncthreads();
        float acc[16];
#pragma unroll
        for (int j = 0; j < 16; ++j) acc[j] = 0.f;
        for (int kc = 0; kc < 128; kc += 4) {
            float4 wv = *(const float4*)&lw[(size_t)ch * DIM + kc];
#pragma unroll
            for (int j = 0; j < 16; ++j)
                acc[j] += wv.x * hs[g * 16 + j][kc] + wv.y * hs[g * 16 + j][kc + 1]
                        + wv.z * hs[g * 16 + j][kc + 2] + wv.w * hs[g * 16 + j][kc + 3];
        }
        float bias = lb[ch];
#pragma unroll
        for (int j = 0; j < 16; ++j) {
            float v = acc[j] + bias;
            int n = n0 + g * 16 + j;
            x[(size_t)n * DIM + ch] = v;
            xb[(size_t)n * DIM + ch] = f2bf(v);
        }
    } else {
        int e = (b - PRE_PREP_BLOCKS - PRE_LIN_BLOCKS) * 256 + t;
        if (e < E) {
            int r = edges[e];
            int col = edges[E + e];
            int slot = atomicAdd(&cnt[r], 1);
            if (slot < CAP) { int2 v; v.x = e; v.y = col; adj2[(size_t)r * CAP + slot] = v; }
        }
    }
}

// ---------------- Kernel 2: edge MLP -> att[E] (R7 structure, frozen) ----------------
__global__ __launch_bounds__(512, 4) void edge_kernel(
    const unsigned short* __restrict__ xb,
    const float* __restrict__ dist, const float* __restrict__ emask,
    const int* __restrict__ edges,
    const unsigned short* __restrict__ w1b, const float* __restrict__ w1last,
    const float* __restrict__ b1,
    const unsigned short* __restrict__ w2b, const float* __restrict__ b2,
    const float* __restrict__ w3, const float* __restrict__ b3v,
    float* __restrict__ att, int E) {
    __shared__ unsigned short buf[EPB * XST];
    __shared__ float part[8][EPB];
    __shared__ float dvals[EPB];
    __shared__ int ridx[EPB], cidx[EPB];

    int tid = threadIdx.x;
    int eb = blockIdx.x * EPB;

    if (tid < EPB) {
        int e = eb + tid;
        ridx[tid] = edges[e];
        cidx[tid] = edges[E + e];
        dvals[tid] = dist[e] * emask[e];
    }
    __syncthreads();

#pragma unroll
    for (int i = 0; i < 4; ++i) {
        int c = tid + 512 * i;
        int r = c >> 5;
        int cb = (c & 31) * 8;
        const unsigned short* src;
        if (cb < 128) src = xb + (size_t)ridx[r] * DIM + cb;
        else          src = xb + (size_t)cidx[r] * DIM + (cb - 128);
        *(bf16x8*)&buf[r * XST + cb] = *(const bf16x8*)src;
    }

    int wave = tid >> 6, lane = tid & 63;
    int lrow = lane & 15, quad = lane >> 4;
    int nb = wave * 32;

    float bias0 = b1[nb + lrow], bias1 = b1[nb + 16 + lrow];
    float wl0 = w1last[nb + lrow], wl1 = w1last[nb + 16 + lrow];
    int n2 = wave * 16 + lrow;
    float bias2 = b2[n2];
    float w3v = w3[n2];

    __syncthreads();

    // ---- layer 1: wave covers 32 of 256 N
    f32x4 z = {0.f, 0.f, 0.f, 0.f};
    f32x4 acc1[4][2];
#pragma unroll
    for (int mt = 0; mt < 4; ++mt)
#pragma unroll
        for (int nt = 0; nt < 2; ++nt) acc1[mt][nt] = z;

    for (int kk = 0; kk < 8; ++kk) {
        int ka = kk * 32 + quad * 8;
        bf16x8 a[4];
#pragma unroll
        for (int mt = 0; mt < 4; ++mt)
            a[mt] = *(bf16x8*)&buf[(mt * 16 + lrow) * XST + ka];
#pragma unroll
        for (int nt = 0; nt < 2; ++nt) {
            int n = nb + nt * 16 + lrow;
            bf16x8 bfrag = *(const bf16x8*)&w1b[(size_t)n * 256 + ka];
#pragma unroll
            for (int mt = 0; mt < 4; ++mt)
                acc1[mt][nt] = __builtin_amdgcn_mfma_f32_16x16x32_bf16(a[mt], bfrag, acc1[mt][nt], 0, 0, 0);
        }
    }
    __syncthreads();   // xcat dead; buf becomes permuted a1

    int colbase = nb + 2 * lrow;
#pragma unroll
    for (int mt = 0; mt < 4; ++mt) {
#pragma unroll
        for (int r = 0; r < 4; ++r) {
            int m = mt * 16 + quad * 4 + r;
            float dv = dvals[m];
            float v0 = fsilu(acc1[mt][0][r] + bias0 + dv * wl0);
            float v1 = fsilu(acc1[mt][1][r] + bias1 + dv * wl1);
            *(unsigned*)&buf[m * XST + colbase] = pack_bf16(v0, v1);
        }
    }
    __syncthreads();

    // ---- layer 2: wave covers 16 of 128 N2 (k-order permuted on both sides)
    f32x4 acc2[4];
#pragma unroll
    for (int mt = 0; mt < 4; ++mt) acc2[mt] = z;

    for (int kk = 0; kk < 8; ++kk) {
        int ka = kk * 32 + quad * 8;
        bf16x8 bfrag = *(const bf16x8*)&w2b[(size_t)n2 * 256 + ka];
#pragma unroll
        for (int mt = 0; mt < 4; ++mt) {
            bf16x8 a = *(bf16x8*)&buf[(mt * 16 + lrow) * XST + ka];
            acc2[mt] = __builtin_amdgcn_mfma_f32_16x16x32_bf16(a, bfrag, acc2[mt], 0, 0, 0);
        }
    }

    // ---- layer 3 in registers
    float s[4][4];
#pragma unroll
    for (int mt = 0; mt < 4; ++mt)
#pragma unroll
        for (int r = 0; r < 4; ++r)
            s[mt][r] = fsilu(acc2[mt][r] + bias2) * w3v;
#pragma unroll
    for (int off = 1; off < 16; off <<= 1) {
#pragma unroll
        for (int mt = 0; mt < 4; ++mt)
#pragma unroll
            for (int r = 0; r < 4; ++r)
                s[mt][r] += __shfl_xor(s[mt][r], off);
    }
    if (lrow == 0) {
#pragma unroll
        for (int mt = 0; mt < 4; ++mt)
#pragma unroll
            for (int r = 0; r < 4; ++r)
                part[wave][mt * 16 + quad * 4 + r] = s[mt][r];
    }
    __syncthreads();

    if (tid < EPB) {
        float ssum = b3v[0];
#pragma unroll
        for (int w = 0; w < 8; ++w) ssum += part[w][tid];
        att[eb + tid] = fsig(ssum) * emask[eb + tid];
    }
}

// ---------------- Kernel 4: aggregate + node MLP + LNs ----------------
// 256 threads = 4 waves, 8 nodes/block: wave = 2 whole nodes (no quarter-split,
// no parts array). Lane = channel-pair; per edge one coalesced 256B row read;
// 4-deep independent load chains. Small LDS -> ~8 blocks/CU resident.
__global__ __launch_bounds__(256) void node_kernel(
    const float* __restrict__ attv, const int2* __restrict__ adj2, const int* __restrict__ cnt,
    const unsigned short* __restrict__ xb,
    const float* __restrict__ x,
    const float* __restrict__ w1, const float* __restrict__ bb1,
    const float* __restrict__ lng, const float* __restrict__ lnb,
    const float* __restrict__ w2, const float* __restrict__ bb2,
    const float* __restrict__ gF, const float* __restrict__ bF,
    float* __restrict__ out, int E) {
    __shared__ float atts[NPB][CAP];
    __shared__ int   cols[NPB][CAP];
    __shared__ float outv[NPB][128];
    __shared__ float bufs[NPB][128];
    __shared__ float mu_s[NPB], rs_s[NPB];
    __shared__ int cnts[NPB];

    int t = threadIdx.x;
    int n0 = blockIdx.x * NPB;

    if (t < NPB) { int c = cnt[n0 + t]; cnts[t] = c > CAP ? CAP : c; }
    __syncthreads();

    // stage lists: group jg = t>>5 (8 groups of 32 lanes), one node each
    {
        int jg = t >> 5, l = t & 31;
        int c = cnts[jg];
        const int2* al = adj2 + (size_t)(n0 + jg) * CAP;
        for (int i = l; i < c; i += 32) {
            int2 v = al[i];
            atts[jg][i] = attv[v.x];
            cols[jg][i] = v.y;
        }
    }
    __syncthreads();

    // gather: wave w owns nodes 2w, 2w+1; lane = channel-pair; 4 chains per node
    int w = t >> 6, lane = t & 63;
#pragma unroll
    for (int jj = 0; jj < 2; ++jj) {
        int j = w * 2 + jj;
        int c = cnts[j];
        float lo0 = 0.f, hi0 = 0.f, lo1 = 0.f, hi1 = 0.f;
        float lo2 = 0.f, hi2 = 0.f, lo3 = 0.f, hi3 = 0.f;
        int i = 0;
        for (; i + 3 < c; i += 4) {
            unsigned u0 = *(const unsigned*)&xb[(size_t)cols[j][i]     * DIM + lane * 2];
            unsigned u1 = *(const unsigned*)&xb[(size_t)cols[j][i + 1] * DIM + lane * 2];
            unsigned u2 = *(const unsigned*)&xb[(size_t)cols[j][i + 2] * DIM + lane * 2];
            unsigned u3 = *(const unsigned*)&xb[(size_t)cols[j][i + 3] * DIM + lane * 2];
            float w0 = atts[j][i], w1v = atts[j][i + 1], w2v = atts[j][i + 2], w3v = atts[j][i + 3];
            lo0 += w0 * bf2f((unsigned short)(u0 & 0xffff)); hi0 += w0 * bf2f((unsigned short)(u0 >> 16));
            lo1 += w1v * bf2f((unsigned short)(u1 & 0xffff)); hi1 += w1v * bf2f((unsigned short)(u1 >> 16));
            lo2 += w2v * bf2f((unsigned short)(u2 & 0xffff)); hi2 += w2v * bf2f((unsigned short)(u2 >> 16));
            lo3 += w3v * bf2f((unsigned short)(u3 & 0xffff)); hi3 += w3v * bf2f((unsigned short)(u3 >> 16));
        }
        for (; i < c; ++i) {
            unsigned u0 = *(const unsigned*)&xb[(size_t)cols[j][i] * DIM + lane * 2];
            float w0 = atts[j][i];
            lo0 += w0 * bf2f((unsigned short)(u0 & 0xffff));
            hi0 += w0 * bf2f((unsigned short)(u0 >> 16));
        }
        outv[j][lane * 2]     = ((lo0 + lo1) + (lo2 + lo3)) * 0.01f;
        outv[j][lane * 2 + 1] = ((hi0 + hi1) + (hi2 + hi3)) * 0.01f;
    }
    __syncthreads();

    // node MLP: thread (h = t>>7, ch = t&127) owns nodes h*4..h*4+3
    int h = t >> 7, ch = t & 127;
    float xres[4];
#pragma unroll
    for (int jj = 0; jj < 4; ++jj)
        xres[jj] = x[(size_t)(n0 + h * 4 + jj) * DIM + ch];

    float a1[4] = {0, 0, 0, 0};
    for (int kc = 0; kc < 128; kc += 4) {
        float4 wv = *(const float4*)&w1[(size_t)ch * DIM + kc];
#pragma unroll
        for (int jj = 0; jj < 4; ++jj) {
            int j = h * 4 + jj;
            a1[jj] += wv.x * outv[j][kc] + wv.y * outv[j][kc + 1] + wv.z * outv[j][kc + 2] + wv.w * outv[j][kc + 3];
        }
    }
    float bias1 = bb1[ch];
#pragma unroll
    for (int jj = 0; jj < 4; ++jj) bufs[h * 4 + jj][ch] = a1[jj] + bias1;
    __syncthreads();

    // LN reduction 1: 8 groups of 32 lanes
    {
        int j = t >> 5, l = t & 31;
        float s = 0.f, qq = 0.f;
#pragma unroll
        for (int i = 0; i < 4; ++i) { float v = bufs[j][l + 32 * i]; s += v; qq += v * v; }
#pragma unroll
        for (int off = 16; off; off >>= 1) { s += __shfl_xor(s, off); qq += __shfl_xor(qq, off); }
        if (l == 0) {
            float mu = s * (1.f / 128.f);
            float var = qq * (1.f / 128.f) - mu * mu;
            mu_s[j] = mu; rs_s[j] = __builtin_amdgcn_rsqf(var + 1e-5f);
        }
    }
    __syncthreads();

    float g = lng[ch], bb = lnb[ch];
    float h2[4];
#pragma unroll
    for (int jj = 0; jj < 4; ++jj) {
        int j = h * 4 + jj;
        h2[jj] = fsilu((bufs[j][ch] - mu_s[j]) * rs_s[j] * g + bb);
    }
    __syncthreads();
#pragma unroll
    for (int jj = 0; jj < 4; ++jj) bufs[h * 4 + jj][ch] = h2[jj];
    __syncthreads();

    float a3[4] = {0, 0, 0, 0};
    for (int kc = 0; kc < 128; kc += 4) {
        float4 wv = *(const float4*)&w2[(size_t)ch * DIM + kc];
#pragma unroll
        for (int jj = 0; jj < 4; ++jj) {
            int j = h * 4 + jj;
            a3[jj] += wv.x * bufs[j][kc] + wv.y * bufs[j][kc + 1] + wv.z * bufs[j][kc + 2] + wv.w * bufs[j][kc + 3];
        }
    }
    float bias2 = bb2[ch];
    float hh[4];
#pragma unroll
    for (int jj = 0; jj < 4; ++jj) hh[jj] = a3[jj] + bias2 + xres[jj];
    __syncthreads();
#pragma unroll
    for (int jj = 0; jj < 4; ++jj) bufs[h * 4 + jj][ch] = hh[jj];
    __syncthreads();

    // LN reduction 2
    {
        int j = t >> 5, l = t & 31;
        float s = 0.f, qq = 0.f;
#pragma unroll
        for (int i = 0; i < 4; ++i) { float v = bufs[j][l + 32 * i]; s += v; qq += v * v; }
#pragma unroll
        for (int off = 16; off; off >>= 1) { s += __shfl_xor(s, off); qq += __shfl_xor(qq, off); }
        if (l == 0) {
            float mu = s * (1.f / 128.f);
            float var = qq * (1.f / 128.f) - mu * mu;
            mu_s[j] = mu; rs_s[j] = __builtin_amdgcn_rsqf(var + 1e-5f);
        }
    }
    __syncthreads();

    float gf = gF[ch], bf = bF[ch];
#pragma unroll
    for (int jj = 0; jj < 4; ++jj) {
        int j = h * 4 + jj;
        float y = (hh[jj] - mu_s[j]) * rs_s[j] * gf + bf;
        out[(size_t)(n0 + j) * DIM + ch] = fsilu(y);
    }
}

extern "C" void kernel_launch(void* const* d_in, const int* in_sizes, int n_in,
                              void* d_out, int out_size, void* d_ws, size_t ws_size,
                              hipStream_t stream) {
    const float* h         = (const float*)d_in[0];
    const float* distances = (const float*)d_in[1];
    const float* edge_mask = (const float*)d_in[3];
    const float* lin_w     = (const float*)d_in[4];
    const float* lin_b     = (const float*)d_in[5];
    const float* att_w1    = (const float*)d_in[6];
    const float* att_b1    = (const float*)d_in[7];
    const float* att_w2    = (const float*)d_in[8];
    const float* att_b2    = (const float*)d_in[9];
    const float* att_w3    = (const float*)d_in[10];
    const float* att_b3    = (const float*)d_in[11];
    const float* nm_w1     = (const float*)d_in[12];
    const float* nm_b1     = (const float*)d_in[13];
    const float* nm_ln_g   = (const float*)d_in[14];
    const float* nm_ln_b   = (const float*)d_in[15];
    const float* nm_w2     = (const float*)d_in[16];
    const float* nm_b2     = (const float*)d_in[17];
    const float* ln_g      = (const float*)d_in[18];
    const float* ln_b      = (const float*)d_in[19];
    const int*   edges     = (const int*)d_in[20];
    float* out = (float*)d_out;

    const int N = N_NODES, E = E_EDGES;

    char* ws = (char*)d_ws;
    float* x            = (float*)ws;            ws += (size_t)N * DIM * 4;
    unsigned short* xb  = (unsigned short*)ws;   ws += (size_t)N * DIM * 2;
    float* attv         = (float*)ws;            ws += (size_t)E * 4;
    int* cnt            = (int*)ws;              ws += (size_t)N * 4;
    int2* adj2          = (int2*)ws;             ws += (size_t)N * CAP * 8;
    unsigned short* w1b = (unsigned short*)ws;   ws += 256 * 256 * 2;
    float* w1last       = (float*)ws;            ws += 256 * 4;
    unsigned short* w2b = (unsigned short*)ws;   ws += 128 * 256 * 2;

    hipMemsetAsync(cnt, 0, (size_t)N * 4, stream);

    pre_kernel<<<PRE_PREP_BLOCKS + PRE_LIN_BLOCKS + PRE_ADJ_BLOCKS, 256, 0, stream>>>(
        att_w1, att_w2, w1b, w1last, w2b,
        h, lin_w, lin_b, x, xb,
        edges, cnt, adj2, E);
    edge_kernel<<<E / EPB, 512, 0, stream>>>(xb, distances, edge_mask, edges,
                                             w1b, w1last, att_b1, w2b, att_b2,
                                             att_w3, att_b3, attv, E);
    node_kernel<<<N / NPB, 256, 0, stream>>>(attv, adj2, cnt, xb, x,
                                             nm_w1, nm_b1, nm_ln_g, nm_ln_b,
                                             nm_w2, nm_b2, ln_g, ln_b, out, E);
}